// Round 11
// baseline (96.358 us; speedup 1.0000x reference)
//
#include <hip/hip_runtime.h>
#include <hip/hip_bf16.h>
#include <hip/hip_fp16.h>

#define SUP 2048
#define NXB 256    // x-slices; grid = (NXB, 4)

// Fixed-point scales
#define SC_CONV 1024.0f       // 2^10, |normalized conv| <= 1
#define SC_X0   512.0f        // 2^9  (high field)
#define SC_XLO  256.0f        // 2^8  (low field; |slice-bin sum| < 2^15)
#define ISC_CONV (1.0f/1024.0f)
#define ISC_X0   (1.0f/512.0f)
#define ISC_XLO  (1.0f/256.0f)

// Exact packed encode: sum of encodings == (sum a)*2^16 + (sum b) in int32
// (borrow from negative low fields pre-compensated).
__device__ __forceinline__ int enc2i(int qa, int qb) {
    return ((qa - (qb < 0 ? 1 : 0)) << 16) + (qb & 0xFFFF);
}
__device__ __forceinline__ int enc2f(float a, float b) {
    return enc2i(__float2int_rn(a), __float2int_rn(b));
}

// ---------------------------------------------------------------------------
// K1: per-pixel inverse L2 norm over 32 conv channels, 4 px/thread, float4
// loads, fp16 output. ~21 us (128 MB cold HBM read at floor).
// ---------------------------------------------------------------------------
__global__ __launch_bounds__(256) void k_invnorm(const float* __restrict__ conv,
                                                 __half* __restrict__ inv,
                                                 int npix) {
    int t = blockIdx.x * blockDim.x + threadIdx.x;
    int p = t * 4;
    if (p + 3 < npix) {
        float4 s = {0.f, 0.f, 0.f, 0.f};
#pragma unroll
        for (int c = 0; c < 32; ++c) {
            float4 v = *(const float4*)(conv + (size_t)c * npix + p);
            s.x += v.x * v.x; s.y += v.y * v.y; s.z += v.z * v.z; s.w += v.w * v.w;
        }
        __half2 h0 = __floats2half2_rn(1.0f / fmaxf(sqrtf(s.x), 1e-12f),
                                       1.0f / fmaxf(sqrtf(s.y), 1e-12f));
        __half2 h1 = __floats2half2_rn(1.0f / fmaxf(sqrtf(s.z), 1e-12f),
                                       1.0f / fmaxf(sqrtf(s.w), 1e-12f));
        *(__half2*)(inv + p) = h0;
        *(__half2*)(inv + p + 2) = h1;
    } else {
        for (; p < npix; ++p) {
            float s = 0.f;
#pragma unroll
            for (int c = 0; c < 32; ++c) {
                float v = conv[(size_t)c * npix + p];
                s += v * v;
            }
            inv[p] = __float2half(1.0f / fmaxf(sqrtf(s), 1e-12f));
        }
    }
}

// ---------------------------------------------------------------------------
// K2: scatter at MAX occupancy. grid (NXB, 4), 512 threads.
// Group g owns channels [8g, 8g+8) as 4 packed int32 rows; row 4:
//   g=0: (x0 @2^9 hi, x1 @2^8 lo); g=1: (count hi, x2 @2^8 lo); g=2,3: unused.
// LDS: 5 x 2048 x int = 40 KiB -> 4 blocks/CU = 160 KiB, 2048 thr/CU (both HW max).
// Per-4px chain: 8 float4 conv + int4 ids + 2x half2 inv (+1 float4 x) ->
// 16-20 LDS int32 atomics. Flush -> fp16 pbuf[NXB][36][SUP] (disjoint rows).
// ---------------------------------------------------------------------------
__global__ __launch_bounds__(512) void k_segacc4(const float* __restrict__ conv,
                                                 const float* __restrict__ x,
                                                 const int* __restrict__ ids,
                                                 const __half* __restrict__ inv,
                                                 float* __restrict__ accum,
                                                 __half* __restrict__ pbuf,
                                                 int npix) {
    __shared__ int sacc[5 * SUP];  // 40 KiB
    int g = blockIdx.y;
    int cb = g * 8;
    for (int i = threadIdx.x; i < 5 * SUP; i += blockDim.x) sacc[i] = 0;
    __syncthreads();

    int per = ((npix + (int)gridDim.x - 1) / (int)gridDim.x + 3) & ~3;
    int start = blockIdx.x * per;
    int end = min(start + per, npix);
    int nvec = (end > start) ? ((end - start) & ~3) : 0;
    int vend = start + nvec;

    const float* cc = conv + (size_t)cb * npix;

    for (int p = start + (int)threadIdx.x * 4; p < vend; p += (int)blockDim.x * 4) {
        int4 id4 = *(const int4*)(ids + p);
        __half2 h01 = *(const __half2*)(inv + p);
        __half2 h23 = *(const __half2*)(inv + p + 2);
        float4 cv[8];
#pragma unroll
        for (int c = 0; c < 8; ++c)
            cv[c] = *(const float4*)(cc + (size_t)c * npix + p);

        float w0 = __low2float(h01) * SC_CONV, w1 = __high2float(h01) * SC_CONV;
        float w2 = __low2float(h23) * SC_CONV, w3 = __high2float(h23) * SC_CONV;

#pragma unroll
        for (int r = 0; r < 4; ++r) {
            float4 a = cv[2 * r], b = cv[2 * r + 1];
            atomicAdd(&sacc[r * SUP + id4.x], enc2f(a.x * w0, b.x * w0));
            atomicAdd(&sacc[r * SUP + id4.y], enc2f(a.y * w1, b.y * w1));
            atomicAdd(&sacc[r * SUP + id4.z], enc2f(a.z * w2, b.z * w2));
            atomicAdd(&sacc[r * SUP + id4.w], enc2f(a.w * w3, b.w * w3));
        }
        if (g == 0) {
            float4 xa = *(const float4*)(x + p);
            float4 xb = *(const float4*)(x + (size_t)npix + p);
            atomicAdd(&sacc[4 * SUP + id4.x], enc2f(xa.x * SC_X0, xb.x * SC_XLO));
            atomicAdd(&sacc[4 * SUP + id4.y], enc2f(xa.y * SC_X0, xb.y * SC_XLO));
            atomicAdd(&sacc[4 * SUP + id4.z], enc2f(xa.z * SC_X0, xb.z * SC_XLO));
            atomicAdd(&sacc[4 * SUP + id4.w], enc2f(xa.w * SC_X0, xb.w * SC_XLO));
        } else if (g == 1) {
            float4 xc = *(const float4*)(x + (size_t)2 * npix + p);
            atomicAdd(&sacc[4 * SUP + id4.x], enc2i(1, __float2int_rn(xc.x * SC_XLO)));
            atomicAdd(&sacc[4 * SUP + id4.y], enc2i(1, __float2int_rn(xc.y * SC_XLO)));
            atomicAdd(&sacc[4 * SUP + id4.z], enc2i(1, __float2int_rn(xc.z * SC_XLO)));
            atomicAdd(&sacc[4 * SUP + id4.w], enc2i(1, __float2int_rn(xc.w * SC_XLO)));
        }
    }
    // scalar tail
    for (int p = vend + (int)threadIdx.x; p < end; p += (int)blockDim.x) {
        int s = ids[p];
        float w = __half2float(inv[p]) * SC_CONV;
#pragma unroll
        for (int r = 0; r < 4; ++r) {
            float a = cc[(size_t)(2 * r) * npix + p];
            float b = cc[(size_t)(2 * r + 1) * npix + p];
            atomicAdd(&sacc[r * SUP + s], enc2f(a * w, b * w));
        }
        if (g == 0) {
            atomicAdd(&sacc[4 * SUP + s],
                      enc2f(x[p] * SC_X0, x[(size_t)npix + p] * SC_XLO));
        } else if (g == 1) {
            atomicAdd(&sacc[4 * SUP + s],
                      enc2i(1, __float2int_rn(x[(size_t)2 * npix + p] * SC_XLO)));
        }
    }
    __syncthreads();

    // decode + flush (rows disjoint across groups)
    int nrows = (g < 2) ? 5 : 4;
    for (int i = threadIdx.x; i < nrows * SUP; i += blockDim.x) {
        int S = sacc[i];
        int qb = (int)(short)(S & 0xFFFF);
        int qa = (S - qb) >> 16;
        int row = i >> 11;
        int s = i & (SUP - 1);
        int hi_row, lo_row;
        float fhi, flo;
        if (row < 4) {
            hi_row = cb + 2 * row; lo_row = hi_row + 1;
            fhi = (float)qa * ISC_CONV;
            flo = (float)qb * ISC_CONV;
        } else if (g == 0) {
            hi_row = 32; lo_row = 33;
            fhi = (float)qa * ISC_X0;
            flo = (float)qb * ISC_XLO;
        } else {
            hi_row = 35; lo_row = 34;
            fhi = (float)qa;              // count
            flo = (float)qb * ISC_XLO;    // x2
        }
        if (pbuf) {
            __half* dst = pbuf + (size_t)blockIdx.x * 36 * SUP;
            dst[hi_row * SUP + s] = __float2half(fhi);
            dst[lo_row * SUP + s] = __float2half(flo);
        } else {
            unsafeAtomicAdd(&accum[hi_row * SUP + s], fhi);
            unsafeAtomicAdd(&accum[lo_row * SUP + s], flo);
        }
    }
}

// ---------------------------------------------------------------------------
// K2b: reduce fp16 per-slice partials -> accum[36][SUP]. 8 elements/thread.
// ---------------------------------------------------------------------------
__global__ __launch_bounds__(256) void k_reduce(const __half* __restrict__ pbuf,
                                                float* __restrict__ accum) {
    int j8 = (blockIdx.x * blockDim.x + threadIdx.x) * 8;
    if (j8 >= 36 * SUP) return;
    float s[8];
#pragma unroll
    for (int k = 0; k < 8; ++k) s[k] = 0.f;
    for (int b = 0; b < NXB; ++b) {
        uint4 u = *(const uint4*)(pbuf + (size_t)b * 36 * SUP + j8);
        __half2 h0 = *reinterpret_cast<__half2*>(&u.x);
        __half2 h1 = *reinterpret_cast<__half2*>(&u.y);
        __half2 h2 = *reinterpret_cast<__half2*>(&u.z);
        __half2 h3 = *reinterpret_cast<__half2*>(&u.w);
        float2 f0 = __half22float2(h0), f1 = __half22float2(h1);
        float2 f2 = __half22float2(h2), f3 = __half22float2(h3);
        s[0] += f0.x; s[1] += f0.y; s[2] += f1.x; s[3] += f1.y;
        s[4] += f2.x; s[5] += f2.y; s[6] += f3.x; s[7] += f3.y;
    }
    float4 o0 = {s[0], s[1], s[2], s[3]};
    float4 o1 = {s[4], s[5], s[6], s[7]};
    *(float4*)(accum + j8) = o0;
    *(float4*)(accum + j8 + 4) = o1;
}

// ---------------------------------------------------------------------------
// K3: per-segment finalize + conv1d. 8 blocks x 256 segments, halo'd LDS tile.
// ---------------------------------------------------------------------------
__device__ __forceinline__ void compute_col(const float* __restrict__ accum,
                                            const float* __restrict__ vit,
                                            int g, float* __restrict__ col) {
    if (g < 0 || g >= SUP) {
#pragma unroll
        for (int c = 0; c < 64; ++c) col[c] = 0.f;
        return;
    }
    float cnt = fmaxf(accum[35 * SUP + g], 1.0f);
    float rc = 1.0f / cnt;
#pragma unroll
    for (int c = 0; c < 32; ++c) col[c] = accum[c * SUP + g] * rc;
    float vs = 0.f;
#pragma unroll
    for (int c = 0; c < 32; ++c) {
        float v = vit[g * 32 + c];
        col[32 + c] = v;
        vs += v * v;
    }
    float vinv = 1.0f / fmaxf(sqrtf(vs), 1e-12f);
#pragma unroll
    for (int c = 0; c < 32; ++c) col[32 + c] *= vinv;
    float ssq = 0.f;
#pragma unroll
    for (int c = 0; c < 64; ++c) ssq += col[c] * col[c];
    float ainv = 1.0f / fmaxf(sqrtf(ssq), 1e-12f);
#pragma unroll
    for (int c = 0; c < 64; ++c) col[c] *= ainv;
}

__global__ __launch_bounds__(256) void k_finalconv(const float* __restrict__ accum,
                                                   const float* __restrict__ vit,
                                                   const float* __restrict__ w,
                                                   const float* __restrict__ bias,
                                                   float* __restrict__ allF_out,
                                                   float* __restrict__ xf_out,
                                                   float* __restrict__ z_out) {
    __shared__ float L[258][65];
    __shared__ float sw[192];
    int t = threadIdx.x;
    int b0 = blockIdx.x * 256;
    if (t < 192) sw[t] = w[t];

    float col[64];
    int g = b0 + t;
    compute_col(accum, vit, g, col);
#pragma unroll
    for (int c = 0; c < 64; ++c) L[t + 1][c] = col[c];
#pragma unroll
    for (int c = 0; c < 64; ++c) allF_out[c * SUP + g] = col[c];
    {
        float cnt = fmaxf(accum[35 * SUP + g], 1.0f);
        float rc = 1.0f / cnt;
#pragma unroll
        for (int c = 0; c < 3; ++c)
            xf_out[c * SUP + g] = accum[(32 + c) * SUP + g] * rc;
    }
    if (t == 0) {
        compute_col(accum, vit, b0 - 1, col);
#pragma unroll
        for (int c = 0; c < 64; ++c) L[0][c] = col[c];
    }
    if (t == 255) {
        compute_col(accum, vit, b0 + 256, col);
#pragma unroll
        for (int c = 0; c < 64; ++c) L[257][c] = col[c];
    }
    __syncthreads();

    float acc = bias[0];
#pragma unroll
    for (int c = 0; c < 64; ++c) {
        acc += sw[c * 3] * L[t][c] + sw[c * 3 + 1] * L[t + 1][c]
             + sw[c * 3 + 2] * L[t + 2][c];
    }
    z_out[b0 + t] = acc;
}

// ---------------------------------------------------------------------------
// K4: BN (batch stats over 2048) + sigmoid + gap.
// ---------------------------------------------------------------------------
__global__ __launch_bounds__(512) void k_head2(const float* __restrict__ z,
                                               const float* __restrict__ gamma,
                                               const float* __restrict__ beta,
                                               float* __restrict__ out) {
    __shared__ float red[8];
    __shared__ float bc[2];
    int tid = threadIdx.x;
    int lane = tid & 63, wid = tid >> 6;

    float zs[4];
#pragma unroll
    for (int j = 0; j < 4; ++j) zs[j] = z[j * 512 + tid];

    float s1 = zs[0] + zs[1] + zs[2] + zs[3];
#pragma unroll
    for (int o = 32; o > 0; o >>= 1) s1 += __shfl_down(s1, o);
    if (lane == 0) red[wid] = s1;
    __syncthreads();
    if (tid == 0) {
        float t = 0.f;
        for (int i = 0; i < 8; ++i) t += red[i];
        bc[0] = t / (float)SUP;
    }
    __syncthreads();
    float mu = bc[0];

    float s2 = 0.f;
#pragma unroll
    for (int j = 0; j < 4; ++j) { float d = zs[j] - mu; s2 += d * d; }
#pragma unroll
    for (int o = 32; o > 0; o >>= 1) s2 += __shfl_down(s2, o);
    __syncthreads();
    if (lane == 0) red[wid] = s2;
    __syncthreads();
    if (tid == 0) {
        float t = 0.f;
        for (int i = 0; i < 8; ++i) t += red[i];
        bc[1] = t / (float)SUP;
    }
    __syncthreads();
    float var = bc[1];

    float invstd = rsqrtf(var + 1e-5f);
    float gm = gamma[0], bt = beta[0];
    float gsum = 0.f;
#pragma unroll
    for (int j = 0; j < 4; ++j) {
        int p = j * 512 + tid;
        float zn = gm * (zs[j] - mu) * invstd + bt;
        float r = 1.0f / (1.0f + expf(-zn));
        out[p] = r;
        gsum += r;
    }
#pragma unroll
    for (int o = 32; o > 0; o >>= 1) gsum += __shfl_down(gsum, o);
    __syncthreads();
    if (lane == 0) red[wid] = gsum;
    __syncthreads();
    if (tid == 0) {
        float t = 0.f;
        for (int i = 0; i < 8; ++i) t += red[i];
        out[SUP] = t / (float)SUP;
    }
}

extern "C" void kernel_launch(void* const* d_in, const int* in_sizes, int n_in,
                              void* d_out, int out_size, void* d_ws, size_t ws_size,
                              hipStream_t stream) {
    const float* x     = (const float*)d_in[0];
    const float* conv  = (const float*)d_in[1];
    const float* vit   = (const float*)d_in[2];
    const int*   ids   = (const int*)d_in[3];
    const float* w     = (const float*)d_in[4];
    const float* b     = (const float*)d_in[5];
    const float* gamma = (const float*)d_in[6];
    const float* beta  = (const float*)d_in[7];
    float* out = (float*)d_out;

    int npix = in_sizes[3];  // B*H*W = 1048576

    // ws layout: inv (npix halves) | accum (36*SUP f32) | zbuf (SUP f32) | pbuf
    __half* inv = (__half*)d_ws;
    float* accum = (float*)((char*)d_ws + (((size_t)npix * 2 + 255) & ~(size_t)255));
    float* zbuf = accum + 36 * SUP;
    __half* pbuf = (__half*)(zbuf + SUP);

    size_t need = ((size_t)npix * 2 + 256) + (36 * SUP + SUP) * sizeof(float)
                + (size_t)NXB * 36 * SUP * sizeof(__half);
    bool useP = ws_size >= need;

    if (!useP) hipMemsetAsync(accum, 0, 36 * SUP * sizeof(float), stream);

    int nquad = (npix + 3) / 4;
    k_invnorm<<<(nquad + 255) / 256, 256, 0, stream>>>(conv, inv, npix);

    dim3 g2(NXB, 4);
    k_segacc4<<<g2, 512, 0, stream>>>(conv, x, ids, inv, accum,
                                      useP ? pbuf : (__half*)nullptr, npix);
    if (useP) {
        k_reduce<<<(36 * SUP / 8 + 255) / 256, 256, 0, stream>>>(pbuf, accum);
    }

    float* allF = out + SUP + 1;                // out offset 2049
    float* xf = allF + 64 * SUP;                // out offset 133121
    k_finalconv<<<SUP / 256, 256, 0, stream>>>(accum, vit, w, b, allF, xf, zbuf);

    k_head2<<<1, 512, 0, stream>>>(zbuf, gamma, beta, out);
}

// Round 12
// 75.479 us; speedup vs baseline: 1.2766x; 1.2766x over previous
//
#include <hip/hip_runtime.h>
#include <hip/hip_bf16.h>
#include <hip/hip_fp16.h>

#define SUP 2048
#define NB  256    // blocks in fused segacc: 1 per CU

// Fixed-point scales
#define SC_CONV 1024.0f       // 2^10, |normalized conv| <= 1
#define SC_X0   512.0f        // 2^9  (high field)
#define SC_XLO  256.0f        // 2^8  (low field: |block-bin sum| < 2^15)
#define ISC_CONV (1.0f/1024.0f)
#define ISC_X0   (1.0f/512.0f)
#define ISC_XLO  (1.0f/256.0f)

// Exact packed encode: sum of encodings == (sum a)*2^16 + (sum b) in int32
// (borrow from negative low fields pre-compensated).
__device__ __forceinline__ int enc2i(int qa, int qb) {
    return ((qa - (qb < 0 ? 1 : 0)) << 16) + (qb & 0xFFFF);
}
__device__ __forceinline__ int enc2f(float a, float b) {
    return enc2i(__float2int_rn(a), __float2int_rn(b));
}

// ---------------------------------------------------------------------------
// K2 (fused): single pass over conv (R6 structure — best measured: 76.5 us
// total). Per 2 pixels: load all 32 channels (float2/lane), inv L2 norm
// inline, 18 packed int32 LDS atomics per pixel. LDS 18 x 2048 x int =
// 144 KiB -> 1 block/CU.
//   rows 0..15: conv channel pairs (2r, 2r+1) @2^10
//   row 16: (x0 @2^9 hi, x1 @2^8 lo)     row 17: (count hi, x2 @2^8 lo)
// Flush decodes -> fp16 pbuf[NB][36][SUP] (or f32 global atomics fallback).
// ---------------------------------------------------------------------------
__global__ __launch_bounds__(1024) void k_segfused(const float* __restrict__ conv,
                                                   const float* __restrict__ x,
                                                   const int* __restrict__ ids,
                                                   float* __restrict__ accum,
                                                   __half* __restrict__ pbuf,
                                                   int npix) {
    __shared__ int sacc[18 * SUP];  // 144 KiB
    for (int i = threadIdx.x; i < 18 * SUP; i += blockDim.x) sacc[i] = 0;
    __syncthreads();

    int per = ((npix + (int)gridDim.x - 1) / (int)gridDim.x + 1) & ~1;  // even
    int start = blockIdx.x * per;
    int end = min(start + per, npix);
    int stride2 = (int)blockDim.x * 2;

    int p = start + (int)threadIdx.x * 2;
    for (; p + 1 < end; p += stride2) {
        int2 id2 = *(const int2*)(ids + p);
        float2 cv[32];
        float s0 = 0.f, s1 = 0.f;
#pragma unroll
        for (int c = 0; c < 32; ++c) {
            cv[c] = *(const float2*)(conv + (size_t)c * npix + p);
            s0 += cv[c].x * cv[c].x;
            s1 += cv[c].y * cv[c].y;
        }
        float i0 = 1.0f / fmaxf(sqrtf(s0), 1e-12f);
        float i1 = 1.0f / fmaxf(sqrtf(s1), 1e-12f);
#pragma unroll
        for (int r = 0; r < 16; ++r) {
            float2 a = cv[2 * r], b = cv[2 * r + 1];
            atomicAdd(&sacc[r * SUP + id2.x],
                      enc2f(a.x * i0 * SC_CONV, b.x * i0 * SC_CONV));
            atomicAdd(&sacc[r * SUP + id2.y],
                      enc2f(a.y * i1 * SC_CONV, b.y * i1 * SC_CONV));
        }
        float2 x0 = *(const float2*)(x + p);
        float2 x1 = *(const float2*)(x + (size_t)npix + p);
        float2 x2 = *(const float2*)(x + (size_t)2 * npix + p);
        atomicAdd(&sacc[16 * SUP + id2.x], enc2f(x0.x * SC_X0, x1.x * SC_XLO));
        atomicAdd(&sacc[16 * SUP + id2.y], enc2f(x0.y * SC_X0, x1.y * SC_XLO));
        atomicAdd(&sacc[17 * SUP + id2.x], enc2i(1, __float2int_rn(x2.x * SC_XLO)));
        atomicAdd(&sacc[17 * SUP + id2.y], enc2i(1, __float2int_rn(x2.y * SC_XLO)));
    }
    // odd-pixel tail (at most one pixel; exactly one thread matches)
    if (p == end - 1) {
        int s = ids[p];
        float cvv[32];
        float ss = 0.f;
#pragma unroll
        for (int c = 0; c < 32; ++c) {
            cvv[c] = conv[(size_t)c * npix + p];
            ss += cvv[c] * cvv[c];
        }
        float iv = 1.0f / fmaxf(sqrtf(ss), 1e-12f);
#pragma unroll
        for (int r = 0; r < 16; ++r)
            atomicAdd(&sacc[r * SUP + s],
                      enc2f(cvv[2 * r] * iv * SC_CONV, cvv[2 * r + 1] * iv * SC_CONV));
        atomicAdd(&sacc[16 * SUP + s],
                  enc2f(x[p] * SC_X0, x[(size_t)npix + p] * SC_XLO));
        atomicAdd(&sacc[17 * SUP + s],
                  enc2i(1, __float2int_rn(x[(size_t)2 * npix + p] * SC_XLO)));
    }
    __syncthreads();

    // decode + flush
    for (int i = threadIdx.x; i < 18 * SUP; i += blockDim.x) {
        int S = sacc[i];
        int qb = (int)(short)(S & 0xFFFF);
        int qa = (S - qb) >> 16;
        int row = i >> 11;
        int s = i & (SUP - 1);
        int hi_row, lo_row;
        float fhi, flo;
        if (row < 16) {
            hi_row = 2 * row; lo_row = 2 * row + 1;
            fhi = (float)qa * ISC_CONV;
            flo = (float)qb * ISC_CONV;
        } else if (row == 16) {
            hi_row = 32; lo_row = 33;
            fhi = (float)qa * ISC_X0;
            flo = (float)qb * ISC_XLO;
        } else {
            hi_row = 35; lo_row = 34;
            fhi = (float)qa;              // count
            flo = (float)qb * ISC_XLO;    // x2
        }
        if (pbuf) {
            __half* dst = pbuf + (size_t)blockIdx.x * 36 * SUP;
            dst[hi_row * SUP + s] = __float2half(fhi);
            dst[lo_row * SUP + s] = __float2half(flo);
        } else {
            unsafeAtomicAdd(&accum[hi_row * SUP + s], fhi);
            unsafeAtomicAdd(&accum[lo_row * SUP + s], flo);
        }
    }
}

// ---------------------------------------------------------------------------
// K2b: reduce fp16 per-block partials -> accum[36][SUP]. 8 elements/thread.
// Regridded 144 blocks x 64 threads (was 36 x 256): spreads the 37.7 MB
// stream over 4x more CUs -> ~4x faster dispatch.
// ---------------------------------------------------------------------------
__global__ __launch_bounds__(64) void k_reduce(const __half* __restrict__ pbuf,
                                               float* __restrict__ accum) {
    int j8 = (blockIdx.x * 64 + threadIdx.x) * 8;
    if (j8 >= 36 * SUP) return;
    float s[8];
#pragma unroll
    for (int k = 0; k < 8; ++k) s[k] = 0.f;
    for (int b = 0; b < NB; ++b) {
        uint4 u = *(const uint4*)(pbuf + (size_t)b * 36 * SUP + j8);
        __half2 h0 = *reinterpret_cast<__half2*>(&u.x);
        __half2 h1 = *reinterpret_cast<__half2*>(&u.y);
        __half2 h2 = *reinterpret_cast<__half2*>(&u.z);
        __half2 h3 = *reinterpret_cast<__half2*>(&u.w);
        float2 f0 = __half22float2(h0), f1 = __half22float2(h1);
        float2 f2 = __half22float2(h2), f3 = __half22float2(h3);
        s[0] += f0.x; s[1] += f0.y; s[2] += f1.x; s[3] += f1.y;
        s[4] += f2.x; s[5] += f2.y; s[6] += f3.x; s[7] += f3.y;
    }
    float4 o0 = {s[0], s[1], s[2], s[3]};
    float4 o1 = {s[4], s[5], s[6], s[7]};
    *(float4*)(accum + j8) = o0;
    *(float4*)(accum + j8 + 4) = o1;
}

// ---------------------------------------------------------------------------
// K3: per-segment finalize + conv1d. 8 blocks x 256 segments, halo'd LDS tile.
// ---------------------------------------------------------------------------
__device__ __forceinline__ void compute_col(const float* __restrict__ accum,
                                            const float* __restrict__ vit,
                                            int g, float* __restrict__ col) {
    if (g < 0 || g >= SUP) {
#pragma unroll
        for (int c = 0; c < 64; ++c) col[c] = 0.f;
        return;
    }
    float cnt = fmaxf(accum[35 * SUP + g], 1.0f);
    float rc = 1.0f / cnt;
#pragma unroll
    for (int c = 0; c < 32; ++c) col[c] = accum[c * SUP + g] * rc;
    float vs = 0.f;
#pragma unroll
    for (int c = 0; c < 32; ++c) {
        float v = vit[g * 32 + c];
        col[32 + c] = v;
        vs += v * v;
    }
    float vinv = 1.0f / fmaxf(sqrtf(vs), 1e-12f);
#pragma unroll
    for (int c = 0; c < 32; ++c) col[32 + c] *= vinv;
    float ssq = 0.f;
#pragma unroll
    for (int c = 0; c < 64; ++c) ssq += col[c] * col[c];
    float ainv = 1.0f / fmaxf(sqrtf(ssq), 1e-12f);
#pragma unroll
    for (int c = 0; c < 64; ++c) col[c] *= ainv;
}

__global__ __launch_bounds__(256) void k_finalconv(const float* __restrict__ accum,
                                                   const float* __restrict__ vit,
                                                   const float* __restrict__ w,
                                                   const float* __restrict__ bias,
                                                   float* __restrict__ allF_out,
                                                   float* __restrict__ xf_out,
                                                   float* __restrict__ z_out) {
    __shared__ float L[258][65];
    __shared__ float sw[192];
    int t = threadIdx.x;
    int b0 = blockIdx.x * 256;
    if (t < 192) sw[t] = w[t];

    float col[64];
    int g = b0 + t;
    compute_col(accum, vit, g, col);
#pragma unroll
    for (int c = 0; c < 64; ++c) L[t + 1][c] = col[c];
#pragma unroll
    for (int c = 0; c < 64; ++c) allF_out[c * SUP + g] = col[c];
    {
        float cnt = fmaxf(accum[35 * SUP + g], 1.0f);
        float rc = 1.0f / cnt;
#pragma unroll
        for (int c = 0; c < 3; ++c)
            xf_out[c * SUP + g] = accum[(32 + c) * SUP + g] * rc;
    }
    if (t == 0) {
        compute_col(accum, vit, b0 - 1, col);
#pragma unroll
        for (int c = 0; c < 64; ++c) L[0][c] = col[c];
    }
    if (t == 255) {
        compute_col(accum, vit, b0 + 256, col);
#pragma unroll
        for (int c = 0; c < 64; ++c) L[257][c] = col[c];
    }
    __syncthreads();

    float acc = bias[0];
#pragma unroll
    for (int c = 0; c < 64; ++c) {
        acc += sw[c * 3] * L[t][c] + sw[c * 3 + 1] * L[t + 1][c]
             + sw[c * 3 + 2] * L[t + 2][c];
    }
    z_out[b0 + t] = acc;
}

// ---------------------------------------------------------------------------
// K4: BN (batch stats over 2048) + sigmoid + gap.
// ---------------------------------------------------------------------------
__global__ __launch_bounds__(512) void k_head2(const float* __restrict__ z,
                                               const float* __restrict__ gamma,
                                               const float* __restrict__ beta,
                                               float* __restrict__ out) {
    __shared__ float red[8];
    __shared__ float bc[2];
    int tid = threadIdx.x;
    int lane = tid & 63, wid = tid >> 6;

    float zs[4];
#pragma unroll
    for (int j = 0; j < 4; ++j) zs[j] = z[j * 512 + tid];

    float s1 = zs[0] + zs[1] + zs[2] + zs[3];
#pragma unroll
    for (int o = 32; o > 0; o >>= 1) s1 += __shfl_down(s1, o);
    if (lane == 0) red[wid] = s1;
    __syncthreads();
    if (tid == 0) {
        float t = 0.f;
        for (int i = 0; i < 8; ++i) t += red[i];
        bc[0] = t / (float)SUP;
    }
    __syncthreads();
    float mu = bc[0];

    float s2 = 0.f;
#pragma unroll
    for (int j = 0; j < 4; ++j) { float d = zs[j] - mu; s2 += d * d; }
#pragma unroll
    for (int o = 32; o > 0; o >>= 1) s2 += __shfl_down(s2, o);
    __syncthreads();
    if (lane == 0) red[wid] = s2;
    __syncthreads();
    if (tid == 0) {
        float t = 0.f;
        for (int i = 0; i < 8; ++i) t += red[i];
        bc[1] = t / (float)SUP;
    }
    __syncthreads();
    float var = bc[1];

    float invstd = rsqrtf(var + 1e-5f);
    float gm = gamma[0], bt = beta[0];
    float gsum = 0.f;
#pragma unroll
    for (int j = 0; j < 4; ++j) {
        int p = j * 512 + tid;
        float zn = gm * (zs[j] - mu) * invstd + bt;
        float r = 1.0f / (1.0f + expf(-zn));
        out[p] = r;
        gsum += r;
    }
#pragma unroll
    for (int o = 32; o > 0; o >>= 1) gsum += __shfl_down(gsum, o);
    __syncthreads();
    if (lane == 0) red[wid] = gsum;
    __syncthreads();
    if (tid == 0) {
        float t = 0.f;
        for (int i = 0; i < 8; ++i) t += red[i];
        out[SUP] = t / (float)SUP;
    }
}

extern "C" void kernel_launch(void* const* d_in, const int* in_sizes, int n_in,
                              void* d_out, int out_size, void* d_ws, size_t ws_size,
                              hipStream_t stream) {
    const float* x     = (const float*)d_in[0];
    const float* conv  = (const float*)d_in[1];
    const float* vit   = (const float*)d_in[2];
    const int*   ids   = (const int*)d_in[3];
    const float* w     = (const float*)d_in[4];
    const float* b     = (const float*)d_in[5];
    const float* gamma = (const float*)d_in[6];
    const float* beta  = (const float*)d_in[7];
    float* out = (float*)d_out;

    int npix = in_sizes[3];  // B*H*W = 1048576

    // ws layout: accum (36*SUP f32) | zbuf (SUP f32) | pbuf (NB*36*SUP halves)
    float* accum = (float*)d_ws;
    float* zbuf = accum + 36 * SUP;
    __half* pbuf = (__half*)(zbuf + SUP);

    size_t need = (36 * SUP + SUP) * sizeof(float)
                + (size_t)NB * 36 * SUP * sizeof(__half);
    bool useP = ws_size >= need;

    if (!useP) hipMemsetAsync(accum, 0, 36 * SUP * sizeof(float), stream);

    k_segfused<<<NB, 1024, 0, stream>>>(conv, x, ids, accum,
                                        useP ? pbuf : (__half*)nullptr, npix);
    if (useP) {
        k_reduce<<<(36 * SUP / 8 + 63) / 64, 64, 0, stream>>>(pbuf, accum);
    }

    float* allF = out + SUP + 1;                // out offset 2049
    float* xf = allF + 64 * SUP;                // out offset 133121
    k_finalconv<<<SUP / 256, 256, 0, stream>>>(accum, vit, w, b, allF, xf, zbuf);

    k_head2<<<1, 512, 0, stream>>>(zbuf, gamma, beta, out);
}